// Round 15
// baseline (4211.828 us; speedup 1.0000x reference)
//
#include <hip/hip_runtime.h>
#include <math.h>
#include <float.h>

// Pointer-network decoder, 1024 sequential steps.
// R14 = R13 (4055us) + detect-path micro-cuts, structure unchanged:
//  (1) per-wave flag polling (lane 0 of each wave polls the block's flag
//      replica; wave gathers its hN quarter immediately) -> the worker's
//      poll->gather barrier is gone; 4 pollers/line.
//  (2) 256 flag replicas stored RELAXED by all agg threads in parallel
//      (flag orders nothing: agg's poll already observed every h-word at
//      MALL; fresh-region gathers can't hit stale L2) -> no release drain.
//  (3) no s_sleep on the critical polls (1 poller/word, 4 pollers/line --
//      no congestion at these densities; removes 64-cyc quantization).

#define SEQ   1024
#define FEAT  256
#define HID   1024
#define NB    256
#define TPB   256
#define AGENT __HIP_MEMORY_SCOPE_AGENT

typedef unsigned long long u64;
typedef unsigned int       u32;

struct alignas(64) Flag { u64 v; u64 pad[7]; };

__device__ __forceinline__ u64 pack_ht(float h, u32 tag) {
  return (u64)__float_as_uint(h) | ((u64)tag << 32);
}
__device__ __forceinline__ float lo_f(u64 d) { return __uint_as_float((u32)d); }
__device__ __forceinline__ u32   hi_u(u64 d) { return (u32)(d >> 32); }

extern "C" __global__ void __launch_bounds__(TPB, 1)
decoder_r14(const float* __restrict__ X,
            const float* __restrict__ ENC,
            const float* __restrict__ W_ih,
            const float* __restrict__ W_hh,
            const float* __restrict__ b_ih,
            const float* __restrict__ b_hh,
            const float* __restrict__ W_out,
            const float* __restrict__ b_out,
            float* __restrict__ out,
            u64* __restrict__ hrec,     // fresh: [SEQ][1024]  else [2][1024]
            u64* __restrict__ lrec,     // [2][1024]
            Flag* __restrict__ flagH,   // [2][256] one replica per block
            int fresh)
{
  const int b   = blockIdx.x;
  const int tid = threadIdx.x;
  const int wv  = tid >> 6;
  const int j   = tid & 15;
  const int l   = tid & 63;
  const int gate = l >> 4;
  const int hrow = b * 4 + wv;
  const int grow = gate * HID + hrow;

  __builtin_amdgcn_fence(__ATOMIC_ACQUIRE, "agent");
  __builtin_amdgcn_sched_barrier(0);

  extern __shared__ float4 lds[];
  float4* whL = lds;                    // 4096
  float4* wiL = lds + 4096;             // 1024
  float4* woL = lds + 5120;             // 1024
  float4* hB0 = lds + 6144;             // 256
  float4* hB1 = lds + 6400;             // 256

  __shared__ float cw_s[4], cw_b[4];
  __shared__ int   cw_i[4];
  __shared__ u32   visw[32];            // agg-only visited bitmap

  const float4* WHH  = (const float4*)W_hh;
  const float4* WIH  = (const float4*)W_ih;
  const float4* WOUT = (const float4*)W_out;
  const float4* X4   = (const float4*)X;

  #pragma unroll
  for (int m = 0; m < 16; ++m)
    whL[m * 256 + tid] = WHH[(size_t)grow * 256 + j + 16 * m];
  #pragma unroll
  for (int m = 0; m < 4; ++m)
    wiL[m * 256 + tid] = WIH[(size_t)grow * 64 + j + 16 * m];
  #pragma unroll
  for (int m = 0; m < 4; ++m)
    woL[m * 256 + tid] = WOUT[(size_t)hrow * 256 + l + 64 * m];
  const float bias_g = b_ih[grow] + b_hh[grow];
  const float bias_o = b_out[hrow];
  const float c0     = ENC[(size_t)(SEQ - 1) * HID + hrow];  // quirk: c0 every step

  hB0[tid] = make_float4(0.f, 0.f, 0.f, 0.f);
  hB1[tid] = make_float4(0.f, 0.f, 0.f, 0.f);
  if (tid < 32) visw[tid] = 0u;
  __syncthreads();

  float4* hC = hB0;
  float4* hN = hB1;

  // x-part precompute for k=0
  float4 xa0, xa1;
  {
    const float4* xr = X4;
    float4 xv0 = xr[j], xv1 = xr[j + 16], xv2 = xr[j + 32], xv3 = xr[j + 48];
    float4 w0 = wiL[tid], w1 = wiL[256 + tid], w2 = wiL[512 + tid], w3 = wiL[768 + tid];
    xa0 = make_float4(0.f, 0.f, 0.f, 0.f);
    xa1 = make_float4(0.f, 0.f, 0.f, 0.f);
    xa0.x = fmaf(w0.x, xv0.x, xa0.x); xa0.y = fmaf(w0.y, xv0.y, xa0.y);
    xa0.z = fmaf(w0.z, xv0.z, xa0.z); xa0.w = fmaf(w0.w, xv0.w, xa0.w);
    xa1.x = fmaf(w1.x, xv1.x, xa1.x); xa1.y = fmaf(w1.y, xv1.y, xa1.y);
    xa1.z = fmaf(w1.z, xv1.z, xa1.z); xa1.w = fmaf(w1.w, xv1.w, xa1.w);
    xa0.x = fmaf(w2.x, xv2.x, xa0.x); xa0.y = fmaf(w2.y, xv2.y, xa0.y);
    xa0.z = fmaf(w2.z, xv2.z, xa0.z); xa0.w = fmaf(w2.w, xv2.w, xa0.w);
    xa1.x = fmaf(w3.x, xv3.x, xa1.x); xa1.y = fmaf(w3.y, xv3.y, xa1.y);
    xa1.z = fmaf(w3.z, xv3.z, xa1.z); xa1.w = fmaf(w3.w, xv3.w, xa1.w);
  }

  for (int k = 0; k <= SEQ; ++k) {
    const int par = k & 1;
    const size_t hb = fresh ? ((size_t)k << 10) : ((size_t)par << 10);

    // ============ Phase A: h(k) from hC; publish straight from registers ===
    if (k < SEQ) {
      float4 a0 = xa0, a1 = xa1;
      #pragma unroll
      for (int m = 0; m < 16; m += 2) {
        float4 w0 = whL[m * 256 + tid],       h0 = hC[j + 16 * m];
        float4 w1 = whL[(m + 1) * 256 + tid], h1 = hC[j + 16 * (m + 1)];
        a0.x = fmaf(w0.x, h0.x, a0.x); a0.y = fmaf(w0.y, h0.y, a0.y);
        a0.z = fmaf(w0.z, h0.z, a0.z); a0.w = fmaf(w0.w, h0.w, a0.w);
        a1.x = fmaf(w1.x, h1.x, a1.x); a1.y = fmaf(w1.y, h1.y, a1.y);
        a1.z = fmaf(w1.z, h1.z, a1.z); a1.w = fmaf(w1.w, h1.w, a1.w);
      }
      float v = ((a0.x + a0.y) + (a0.z + a0.w)) + ((a1.x + a1.y) + (a1.z + a1.w));
      v += __shfl_xor(v, 1); v += __shfl_xor(v, 2);
      v += __shfl_xor(v, 4); v += __shfl_xor(v, 8);
      v += bias_g;
      float act = (gate == 2) ? tanhf(v) : 1.f / (1.f + expf(-v));
      float ai = __shfl(act, wv * 64 + 0),  af = __shfl(act, wv * 64 + 16);
      float ag = __shfl(act, wv * 64 + 32), ao = __shfl(act, wv * 64 + 48);
      if (l == 0) {
        float cc = fmaf(af, c0, ai * ag);   // quirk: c0 re-used every step
        float hv = ao * tanhf(cc);
        __hip_atomic_store(&hrec[hb + hrow], pack_ht(hv, (u32)(k + 1)),
                           __ATOMIC_RELAXED, AGENT);
      }
    }

    // ============ Phase B: logits(k-1) from hC; tag-in-word publish ========
    if (k > 0) {
      float4 a0 = make_float4(0.f, 0.f, 0.f, 0.f);
      float4 a1 = make_float4(0.f, 0.f, 0.f, 0.f);
      #pragma unroll
      for (int m = 0; m < 4; m += 2) {
        float4 w0 = woL[m * 256 + tid],       h0 = hC[l + 64 * m];
        float4 w1 = woL[(m + 1) * 256 + tid], h1 = hC[l + 64 * (m + 1)];
        a0.x = fmaf(w0.x, h0.x, a0.x); a0.y = fmaf(w0.y, h0.y, a0.y);
        a0.z = fmaf(w0.z, h0.z, a0.z); a0.w = fmaf(w0.w, h0.w, a0.w);
        a1.x = fmaf(w1.x, h1.x, a1.x); a1.y = fmaf(w1.y, h1.y, a1.y);
        a1.z = fmaf(w1.z, h1.z, a1.z); a1.w = fmaf(w1.w, h1.w, a1.w);
      }
      float lv = ((a0.x + a0.y) + (a0.z + a0.w)) + ((a1.x + a1.y) + (a1.z + a1.w));
      #pragma unroll
      for (int m = 1; m < 64; m <<= 1) lv += __shfl_xor(lv, m);
      if (l == 0) {
        float lt = lv + bias_o;
        __hip_atomic_store(&lrec[(((k - 1) & 1) << 10) + hrow],
                           pack_ht(lt, (u32)k), __ATOMIC_RELAXED, AGENT);
      }
    }

    // ---- x-part precompute for step k+1 (shadowed into the wait) ----
    if (k + 1 < SEQ) {
      const float4* xr = X4 + (size_t)(k + 1) * 64;
      float4 xv0 = xr[j], xv1 = xr[j + 16], xv2 = xr[j + 32], xv3 = xr[j + 48];
      float4 w0 = wiL[tid], w1 = wiL[256 + tid], w2 = wiL[512 + tid], w3 = wiL[768 + tid];
      xa0 = make_float4(0.f, 0.f, 0.f, 0.f);
      xa1 = make_float4(0.f, 0.f, 0.f, 0.f);
      xa0.x = fmaf(w0.x, xv0.x, xa0.x); xa0.y = fmaf(w0.y, xv0.y, xa0.y);
      xa0.z = fmaf(w0.z, xv0.z, xa0.z); xa0.w = fmaf(w0.w, xv0.w, xa0.w);
      xa1.x = fmaf(w1.x, xv1.x, xa1.x); xa1.y = fmaf(w1.y, xv1.y, xa1.y);
      xa1.z = fmaf(w1.z, xv1.z, xa1.z); xa1.w = fmaf(w1.w, xv1.w, xa1.w);
      xa0.x = fmaf(w2.x, xv2.x, xa0.x); xa0.y = fmaf(w2.y, xv2.y, xa0.y);
      xa0.z = fmaf(w2.z, xv2.z, xa0.z); xa0.w = fmaf(w2.w, xv2.w, xa0.w);
      xa1.x = fmaf(w3.x, xv3.x, xa1.x); xa1.y = fmaf(w3.y, xv3.y, xa1.y);
      xa1.z = fmaf(w3.z, xv3.z, xa1.z); xa1.w = fmaf(w3.w, xv3.w, xa1.w);
    }

    if (b == 0) {
      // ===== aggregator: rendezvous on 4 h-words (yields h directly) =====
      u64 w0 = 0, w1 = 0, w2 = 0, w3 = 0;
      if (k < SEQ) {
        u64* rp = hrec + hb + 4 * (size_t)tid;
        const u32 t = (u32)(k + 1);
        for (;;) {
          w0 = __hip_atomic_load(&rp[0], __ATOMIC_RELAXED, AGENT);
          w1 = __hip_atomic_load(&rp[1], __ATOMIC_RELAXED, AGENT);
          w2 = __hip_atomic_load(&rp[2], __ATOMIC_RELAXED, AGENT);
          w3 = __hip_atomic_load(&rp[3], __ATOMIC_RELAXED, AGENT);
          if (hi_u(w0) == t && hi_u(w1) == t && hi_u(w2) == t && hi_u(w3) == t) break;
        }
        __syncthreads();                  // all 1024 rows confirmed at MALL
        // 256 replicas, one per worker block, RELAXED (flag orders nothing)
        __hip_atomic_store(&flagH[par * 256 + tid].v, (u64)(u32)(k + 1),
                           __ATOMIC_RELAXED, AGENT);
        __builtin_amdgcn_sched_barrier(0);
      }

      if (k >= 1) {                       // logits shadow: self-validating words
        u64* lp = lrec + (((size_t)((k - 1) & 1)) << 10) + 4 * (size_t)tid;
        const u32 t = (u32)k;
        u64 p0, p1, p2, p3;
        for (;;) {
          p0 = __hip_atomic_load(&lp[0], __ATOMIC_RELAXED, AGENT);
          p1 = __hip_atomic_load(&lp[1], __ATOMIC_RELAXED, AGENT);
          p2 = __hip_atomic_load(&lp[2], __ATOMIC_RELAXED, AGENT);
          p3 = __hip_atomic_load(&lp[3], __ATOMIC_RELAXED, AGENT);
          if (hi_u(p0) == t && hi_u(p1) == t && hi_u(p2) == t && hi_u(p3) == t) break;
        }
        float l0 = lo_f(p0), l1 = lo_f(p1), l2 = lo_f(p2), l3 = lo_f(p3);
        float s_p = ((expf(l0) + expf(l1)) + expf(l2)) + expf(l3);
        u32 vb = visw[tid >> 3] >> ((tid & 7) * 4);
        float b_p = -FLT_MAX; int i_p = 0x7fffffff;
        if (!(vb & 1u) && l0 > b_p) { b_p = l0; i_p = 4 * tid; }
        if (!(vb & 2u) && l1 > b_p) { b_p = l1; i_p = 4 * tid + 1; }
        if (!(vb & 4u) && l2 > b_p) { b_p = l2; i_p = 4 * tid + 2; }
        if (!(vb & 8u) && l3 > b_p) { b_p = l3; i_p = 4 * tid + 3; }
        #pragma unroll
        for (int m = 1; m < 64; m <<= 1) {
          float s2 = __shfl_xor(s_p, m);
          float b2 = __shfl_xor(b_p, m);
          int   i2 = __shfl_xor(i_p, m);
          s_p += s2;
          if (b2 > b_p || (b2 == b_p && i2 < i_p)) { b_p = b2; i_p = i2; }
        }
        if (l == 0) { cw_s[wv] = s_p; cw_b[wv] = b_p; cw_i[wv] = i_p; }
        __syncthreads();
        if (tid == 0) {
          float s = cw_s[0], bv = cw_b[0]; int bi = cw_i[0];
          #pragma unroll
          for (int q = 1; q < 4; ++q) {
            s += cw_s[q];
            if (cw_b[q] > bv || (cw_b[q] == bv && cw_i[q] < bi)) { bv = cw_b[q]; bi = cw_i[q]; }
          }
          out[k - 1]       = (float)bi;
          out[SEQ + k - 1] = bv - logf(s);
          visw[bi >> 5] |= 1u << (bi & 31);
        }
      }
      if (k == SEQ) break;
      hN[tid] = make_float4(lo_f(w0), lo_f(w1), lo_f(w2), lo_f(w3));
    } else {
      if (k == SEQ) break;    // final logits published; agg finishes alone
      // ---- per-wave detect: lane 0 polls the block replica, no sleep ----
      if (l == 0) {
        Flag* fp = &flagH[par * 256 + b];
        u64 f = __hip_atomic_load(&fp->v, __ATOMIC_RELAXED, AGENT);
        while ((u32)f != (u32)(k + 1))
          f = __hip_atomic_load(&fp->v, __ATOMIC_RELAXED, AGENT);
      }
      __builtin_amdgcn_sched_barrier(0);   // wave reconverged -> h at MALL
      if (fresh) {            // cached, L2-amplified (fresh addresses)
        const ulonglong2* hp = (const ulonglong2*)(hrec + hb);
        ulonglong2 q0 = hp[2 * tid], q1 = hp[2 * tid + 1];
        hN[tid] = make_float4(lo_f(q0.x), lo_f(q0.y), lo_f(q1.x), lo_f(q1.y));
      } else {                // fallback: atomic gather (parity addresses)
        u64* rp = hrec + hb + 4 * (size_t)tid;
        u64 a0 = __hip_atomic_load(&rp[0], __ATOMIC_RELAXED, AGENT);
        u64 a1 = __hip_atomic_load(&rp[1], __ATOMIC_RELAXED, AGENT);
        u64 a2 = __hip_atomic_load(&rp[2], __ATOMIC_RELAXED, AGENT);
        u64 a3 = __hip_atomic_load(&rp[3], __ATOMIC_RELAXED, AGENT);
        hN[tid] = make_float4(lo_f(a0), lo_f(a1), lo_f(a2), lo_f(a3));
      }
    }
    __syncthreads();          // hN complete (single worker barrier per step)
    float4* t = hC; hC = hN; hN = t;
  }
}

extern "C" void kernel_launch(void* const* d_in, const int* in_sizes, int n_in,
                              void* d_out, int out_size, void* d_ws, size_t ws_size,
                              hipStream_t stream) {
  const float* X     = (const float*)d_in[0];
  const float* ENC   = (const float*)d_in[1];
  const float* W_ih  = (const float*)d_in[2];
  const float* W_hh  = (const float*)d_in[3];
  const float* b_ih  = (const float*)d_in[4];
  const float* b_hh  = (const float*)d_in[5];
  const float* W_out = (const float*)d_in[6];
  const float* b_out = (const float*)d_in[7];
  float* out = (float*)d_out;

  const int lds_bytes = (16 * 256 + 1024 + 1024 + 512) * 16;   // 106496

  const size_t hrec_fresh = (size_t)SEQ * 1024 * sizeof(u64);  // 8 MB
  const size_t hrec_par   = (size_t)2 * 1024 * sizeof(u64);    // 16 KB
  const size_t lrec_b     = (size_t)2 * 1024 * sizeof(u64);    // 16 KB
  const size_t flag_b     = (size_t)2 * 256 * sizeof(Flag);    // 32 KB

  const int fresh = (ws_size >= hrec_fresh + lrec_b + flag_b) ? 1 : 0;
  const size_t hsz = fresh ? hrec_fresh : hrec_par;

  u64*  hrec  = (u64*)d_ws;
  u64*  lrec  = (u64*)((char*)d_ws + hsz);
  Flag* flagH = (Flag*)((char*)d_ws + hsz + lrec_b);

  (void)hipFuncSetAttribute(
      reinterpret_cast<const void*>(&decoder_r14),
      hipFuncAttributeMaxDynamicSharedMemorySize, lds_bytes);
  decoder_r14<<<NB, TPB, lds_bytes, stream>>>(
      X, ENC, W_ih, W_hh, b_ih, b_hh, W_out, b_out, out,
      hrec, lrec, flagH, fresh);
}

// Round 16
// 3997.537 us; speedup vs baseline: 1.0536x; 1.0536x over previous
//
#include <hip/hip_runtime.h>
#include <math.h>
#include <float.h>

// Pointer-network decoder, 1024 sequential steps.
// R15 = exact revert to R13 (4055us, session best). R14's micro-cuts
// (256 relaxed flag replicas, no-sleep polls, per-wave detect) regressed
// +4%: the flag broadcast added 16KB/step of store traffic on the critical
// moment and no-sleep polling congested the MALL (third confirmation of
// that lesson). Structure: tag-in-word publishes (zero release drains),
// single agg rendezvous that doubles as the agg gather, one flag hop
// (32 release replicas, <=8 pollers/line), s_sleep(1) on all spins,
// L2-amplified cached worker gather from fresh per-step addresses,
// logits processed entirely in the agg's shadow.

#define SEQ   1024
#define FEAT  256
#define HID   1024
#define NB    256
#define TPB   256
#define AGENT __HIP_MEMORY_SCOPE_AGENT

typedef unsigned long long u64;
typedef unsigned int       u32;

struct alignas(64) Flag { u64 v; u64 pad[7]; };

__device__ __forceinline__ u64 pack_ht(float h, u32 tag) {
  return (u64)__float_as_uint(h) | ((u64)tag << 32);
}
__device__ __forceinline__ float lo_f(u64 d) { return __uint_as_float((u32)d); }
__device__ __forceinline__ u32   hi_u(u64 d) { return (u32)(d >> 32); }

extern "C" __global__ void __launch_bounds__(TPB, 1)
decoder_r13(const float* __restrict__ X,
            const float* __restrict__ ENC,
            const float* __restrict__ W_ih,
            const float* __restrict__ W_hh,
            const float* __restrict__ b_ih,
            const float* __restrict__ b_hh,
            const float* __restrict__ W_out,
            const float* __restrict__ b_out,
            float* __restrict__ out,
            u64* __restrict__ hrec,     // fresh: [SEQ][1024]  else [2][1024]
            u64* __restrict__ lrec,     // [2][1024]
            Flag* __restrict__ flagH,   // [2][32] replicas
            int fresh)
{
  const int b   = blockIdx.x;
  const int tid = threadIdx.x;
  const int wv  = tid >> 6;
  const int j   = tid & 15;
  const int l   = tid & 63;
  const int gate = l >> 4;
  const int hrow = b * 4 + wv;
  const int grow = gate * HID + hrow;

  __builtin_amdgcn_fence(__ATOMIC_ACQUIRE, "agent");
  __builtin_amdgcn_sched_barrier(0);

  extern __shared__ float4 lds[];
  float4* whL = lds;                    // 4096
  float4* wiL = lds + 4096;             // 1024
  float4* woL = lds + 5120;             // 1024
  float4* hB0 = lds + 6144;             // 256
  float4* hB1 = lds + 6400;             // 256

  __shared__ float cw_s[4], cw_b[4];
  __shared__ int   cw_i[4];
  __shared__ u32   visw[32];            // agg-only visited bitmap

  const float4* WHH  = (const float4*)W_hh;
  const float4* WIH  = (const float4*)W_ih;
  const float4* WOUT = (const float4*)W_out;
  const float4* X4   = (const float4*)X;

  #pragma unroll
  for (int m = 0; m < 16; ++m)
    whL[m * 256 + tid] = WHH[(size_t)grow * 256 + j + 16 * m];
  #pragma unroll
  for (int m = 0; m < 4; ++m)
    wiL[m * 256 + tid] = WIH[(size_t)grow * 64 + j + 16 * m];
  #pragma unroll
  for (int m = 0; m < 4; ++m)
    woL[m * 256 + tid] = WOUT[(size_t)hrow * 256 + l + 64 * m];
  const float bias_g = b_ih[grow] + b_hh[grow];
  const float bias_o = b_out[hrow];
  const float c0     = ENC[(size_t)(SEQ - 1) * HID + hrow];  // quirk: c0 every step

  hB0[tid] = make_float4(0.f, 0.f, 0.f, 0.f);
  hB1[tid] = make_float4(0.f, 0.f, 0.f, 0.f);
  if (tid < 32) visw[tid] = 0u;
  __syncthreads();

  float4* hC = hB0;
  float4* hN = hB1;

  // x-part precompute for k=0
  float4 xa0, xa1;
  {
    const float4* xr = X4;
    float4 xv0 = xr[j], xv1 = xr[j + 16], xv2 = xr[j + 32], xv3 = xr[j + 48];
    float4 w0 = wiL[tid], w1 = wiL[256 + tid], w2 = wiL[512 + tid], w3 = wiL[768 + tid];
    xa0 = make_float4(0.f, 0.f, 0.f, 0.f);
    xa1 = make_float4(0.f, 0.f, 0.f, 0.f);
    xa0.x = fmaf(w0.x, xv0.x, xa0.x); xa0.y = fmaf(w0.y, xv0.y, xa0.y);
    xa0.z = fmaf(w0.z, xv0.z, xa0.z); xa0.w = fmaf(w0.w, xv0.w, xa0.w);
    xa1.x = fmaf(w1.x, xv1.x, xa1.x); xa1.y = fmaf(w1.y, xv1.y, xa1.y);
    xa1.z = fmaf(w1.z, xv1.z, xa1.z); xa1.w = fmaf(w1.w, xv1.w, xa1.w);
    xa0.x = fmaf(w2.x, xv2.x, xa0.x); xa0.y = fmaf(w2.y, xv2.y, xa0.y);
    xa0.z = fmaf(w2.z, xv2.z, xa0.z); xa0.w = fmaf(w2.w, xv2.w, xa0.w);
    xa1.x = fmaf(w3.x, xv3.x, xa1.x); xa1.y = fmaf(w3.y, xv3.y, xa1.y);
    xa1.z = fmaf(w3.z, xv3.z, xa1.z); xa1.w = fmaf(w3.w, xv3.w, xa1.w);
  }

  for (int k = 0; k <= SEQ; ++k) {
    const int par = k & 1;
    const size_t hb = fresh ? ((size_t)k << 10) : ((size_t)par << 10);

    // ============ Phase A: h(k) from hC; publish straight from registers ===
    if (k < SEQ) {
      float4 a0 = xa0, a1 = xa1;
      #pragma unroll
      for (int m = 0; m < 16; m += 2) {
        float4 w0 = whL[m * 256 + tid],       h0 = hC[j + 16 * m];
        float4 w1 = whL[(m + 1) * 256 + tid], h1 = hC[j + 16 * (m + 1)];
        a0.x = fmaf(w0.x, h0.x, a0.x); a0.y = fmaf(w0.y, h0.y, a0.y);
        a0.z = fmaf(w0.z, h0.z, a0.z); a0.w = fmaf(w0.w, h0.w, a0.w);
        a1.x = fmaf(w1.x, h1.x, a1.x); a1.y = fmaf(w1.y, h1.y, a1.y);
        a1.z = fmaf(w1.z, h1.z, a1.z); a1.w = fmaf(w1.w, h1.w, a1.w);
      }
      float v = ((a0.x + a0.y) + (a0.z + a0.w)) + ((a1.x + a1.y) + (a1.z + a1.w));
      v += __shfl_xor(v, 1); v += __shfl_xor(v, 2);
      v += __shfl_xor(v, 4); v += __shfl_xor(v, 8);
      v += bias_g;
      float act = (gate == 2) ? tanhf(v) : 1.f / (1.f + expf(-v));
      float ai = __shfl(act, wv * 64 + 0),  af = __shfl(act, wv * 64 + 16);
      float ag = __shfl(act, wv * 64 + 32), ao = __shfl(act, wv * 64 + 48);
      if (l == 0) {
        float cc = fmaf(af, c0, ai * ag);   // quirk: c0 re-used every step
        float hv = ao * tanhf(cc);
        __hip_atomic_store(&hrec[hb + hrow], pack_ht(hv, (u32)(k + 1)),
                           __ATOMIC_RELAXED, AGENT);
      }
    }

    // ============ Phase B: logits(k-1) from hC; tag-in-word publish ========
    if (k > 0) {
      float4 a0 = make_float4(0.f, 0.f, 0.f, 0.f);
      float4 a1 = make_float4(0.f, 0.f, 0.f, 0.f);
      #pragma unroll
      for (int m = 0; m < 4; m += 2) {
        float4 w0 = woL[m * 256 + tid],       h0 = hC[l + 64 * m];
        float4 w1 = woL[(m + 1) * 256 + tid], h1 = hC[l + 64 * (m + 1)];
        a0.x = fmaf(w0.x, h0.x, a0.x); a0.y = fmaf(w0.y, h0.y, a0.y);
        a0.z = fmaf(w0.z, h0.z, a0.z); a0.w = fmaf(w0.w, h0.w, a0.w);
        a1.x = fmaf(w1.x, h1.x, a1.x); a1.y = fmaf(w1.y, h1.y, a1.y);
        a1.z = fmaf(w1.z, h1.z, a1.z); a1.w = fmaf(w1.w, h1.w, a1.w);
      }
      float lv = ((a0.x + a0.y) + (a0.z + a0.w)) + ((a1.x + a1.y) + (a1.z + a1.w));
      #pragma unroll
      for (int m = 1; m < 64; m <<= 1) lv += __shfl_xor(lv, m);
      if (l == 0) {
        float lt = lv + bias_o;
        __hip_atomic_store(&lrec[(((k - 1) & 1) << 10) + hrow],
                           pack_ht(lt, (u32)k), __ATOMIC_RELAXED, AGENT);
      }
    }

    // ---- x-part precompute for step k+1 (shadowed into the wait) ----
    if (k + 1 < SEQ) {
      const float4* xr = X4 + (size_t)(k + 1) * 64;
      float4 xv0 = xr[j], xv1 = xr[j + 16], xv2 = xr[j + 32], xv3 = xr[j + 48];
      float4 w0 = wiL[tid], w1 = wiL[256 + tid], w2 = wiL[512 + tid], w3 = wiL[768 + tid];
      xa0 = make_float4(0.f, 0.f, 0.f, 0.f);
      xa1 = make_float4(0.f, 0.f, 0.f, 0.f);
      xa0.x = fmaf(w0.x, xv0.x, xa0.x); xa0.y = fmaf(w0.y, xv0.y, xa0.y);
      xa0.z = fmaf(w0.z, xv0.z, xa0.z); xa0.w = fmaf(w0.w, xv0.w, xa0.w);
      xa1.x = fmaf(w1.x, xv1.x, xa1.x); xa1.y = fmaf(w1.y, xv1.y, xa1.y);
      xa1.z = fmaf(w1.z, xv1.z, xa1.z); xa1.w = fmaf(w1.w, xv1.w, xa1.w);
      xa0.x = fmaf(w2.x, xv2.x, xa0.x); xa0.y = fmaf(w2.y, xv2.y, xa0.y);
      xa0.z = fmaf(w2.z, xv2.z, xa0.z); xa0.w = fmaf(w2.w, xv2.w, xa0.w);
      xa1.x = fmaf(w3.x, xv3.x, xa1.x); xa1.y = fmaf(w3.y, xv3.y, xa1.y);
      xa1.z = fmaf(w3.z, xv3.z, xa1.z); xa1.w = fmaf(w3.w, xv3.w, xa1.w);
    }

    if (b == 0) {
      // ===== aggregator: rendezvous on 4 h-words (yields h directly) =====
      u64 w0 = 0, w1 = 0, w2 = 0, w3 = 0;
      if (k < SEQ) {
        u64* rp = hrec + hb + 4 * (size_t)tid;
        const u32 t = (u32)(k + 1);
        for (;;) {
          w0 = __hip_atomic_load(&rp[0], __ATOMIC_RELAXED, AGENT);
          w1 = __hip_atomic_load(&rp[1], __ATOMIC_RELAXED, AGENT);
          w2 = __hip_atomic_load(&rp[2], __ATOMIC_RELAXED, AGENT);
          w3 = __hip_atomic_load(&rp[3], __ATOMIC_RELAXED, AGENT);
          if (hi_u(w0) == t && hi_u(w1) == t && hi_u(w2) == t && hi_u(w3) == t) break;
          __builtin_amdgcn_s_sleep(1);
        }
        __syncthreads();                  // all 1024 rows confirmed at MALL
        if (tid < 32)
          __hip_atomic_store(&flagH[par * 32 + tid].v, (u64)(u32)(k + 1),
                             __ATOMIC_RELEASE, AGENT);
        __builtin_amdgcn_sched_barrier(0);
      }

      if (k >= 1) {                       // logits shadow: self-validating words
        u64* lp = lrec + (((size_t)((k - 1) & 1)) << 10) + 4 * (size_t)tid;
        const u32 t = (u32)k;
        u64 p0, p1, p2, p3;
        for (;;) {
          p0 = __hip_atomic_load(&lp[0], __ATOMIC_RELAXED, AGENT);
          p1 = __hip_atomic_load(&lp[1], __ATOMIC_RELAXED, AGENT);
          p2 = __hip_atomic_load(&lp[2], __ATOMIC_RELAXED, AGENT);
          p3 = __hip_atomic_load(&lp[3], __ATOMIC_RELAXED, AGENT);
          if (hi_u(p0) == t && hi_u(p1) == t && hi_u(p2) == t && hi_u(p3) == t) break;
          __builtin_amdgcn_s_sleep(1);
        }
        float l0 = lo_f(p0), l1 = lo_f(p1), l2 = lo_f(p2), l3 = lo_f(p3);
        // same float association as R10: per-4 exp sum, then butterfly
        float s_p = ((expf(l0) + expf(l1)) + expf(l2)) + expf(l3);
        u32 vb = visw[tid >> 3] >> ((tid & 7) * 4);
        float b_p = -FLT_MAX; int i_p = 0x7fffffff;
        if (!(vb & 1u) && l0 > b_p) { b_p = l0; i_p = 4 * tid; }
        if (!(vb & 2u) && l1 > b_p) { b_p = l1; i_p = 4 * tid + 1; }
        if (!(vb & 4u) && l2 > b_p) { b_p = l2; i_p = 4 * tid + 2; }
        if (!(vb & 8u) && l3 > b_p) { b_p = l3; i_p = 4 * tid + 3; }
        #pragma unroll
        for (int m = 1; m < 64; m <<= 1) {
          float s2 = __shfl_xor(s_p, m);
          float b2 = __shfl_xor(b_p, m);
          int   i2 = __shfl_xor(i_p, m);
          s_p += s2;
          if (b2 > b_p || (b2 == b_p && i2 < i_p)) { b_p = b2; i_p = i2; }
        }
        if (l == 0) { cw_s[wv] = s_p; cw_b[wv] = b_p; cw_i[wv] = i_p; }
        __syncthreads();
        if (tid == 0) {
          float s = cw_s[0], bv = cw_b[0]; int bi = cw_i[0];
          #pragma unroll
          for (int q = 1; q < 4; ++q) {
            s += cw_s[q];
            if (cw_b[q] > bv || (cw_b[q] == bv && cw_i[q] < bi)) { bv = cw_b[q]; bi = cw_i[q]; }
          }
          out[k - 1]       = (float)bi;
          out[SEQ + k - 1] = bv - logf(s);
          visw[bi >> 5] |= 1u << (bi & 31);
        }
      }
      if (k == SEQ) break;
      hN[tid] = make_float4(lo_f(w0), lo_f(w1), lo_f(w2), lo_f(w3));
    } else {
      if (k == SEQ) break;    // final logits published; agg finishes alone
      if (tid == 0) {
        Flag* fp = &flagH[par * 32 + (b >> 3)];
        u64 f = __hip_atomic_load(&fp->v, __ATOMIC_RELAXED, AGENT);
        while ((u32)f != (u32)(k + 1)) {
          __builtin_amdgcn_s_sleep(1);
          f = __hip_atomic_load(&fp->v, __ATOMIC_RELAXED, AGENT);
        }
      }
      __syncthreads();        // flagH observed -> all h-words at MALL
      __builtin_amdgcn_sched_barrier(0);
      if (fresh) {            // cached, L2-amplified (fresh addresses)
        const ulonglong2* hp = (const ulonglong2*)(hrec + hb);
        ulonglong2 q0 = hp[2 * tid], q1 = hp[2 * tid + 1];
        hN[tid] = make_float4(lo_f(q0.x), lo_f(q0.y), lo_f(q1.x), lo_f(q1.y));
      } else {                // fallback: atomic gather (parity addresses)
        u64* rp = hrec + hb + 4 * (size_t)tid;
        u64 a0 = __hip_atomic_load(&rp[0], __ATOMIC_RELAXED, AGENT);
        u64 a1 = __hip_atomic_load(&rp[1], __ATOMIC_RELAXED, AGENT);
        u64 a2 = __hip_atomic_load(&rp[2], __ATOMIC_RELAXED, AGENT);
        u64 a3 = __hip_atomic_load(&rp[3], __ATOMIC_RELAXED, AGENT);
        hN[tid] = make_float4(lo_f(a0), lo_f(a1), lo_f(a2), lo_f(a3));
      }
    }
    __syncthreads();          // hN complete
    float4* t = hC; hC = hN; hN = t;
  }
}

extern "C" void kernel_launch(void* const* d_in, const int* in_sizes, int n_in,
                              void* d_out, int out_size, void* d_ws, size_t ws_size,
                              hipStream_t stream) {
  const float* X     = (const float*)d_in[0];
  const float* ENC   = (const float*)d_in[1];
  const float* W_ih  = (const float*)d_in[2];
  const float* W_hh  = (const float*)d_in[3];
  const float* b_ih  = (const float*)d_in[4];
  const float* b_hh  = (const float*)d_in[5];
  const float* W_out = (const float*)d_in[6];
  const float* b_out = (const float*)d_in[7];
  float* out = (float*)d_out;

  const int lds_bytes = (16 * 256 + 1024 + 1024 + 512) * 16;   // 106496

  const size_t hrec_fresh = (size_t)SEQ * 1024 * sizeof(u64);  // 8 MB
  const size_t hrec_par   = (size_t)2 * 1024 * sizeof(u64);    // 16 KB
  const size_t lrec_b     = (size_t)2 * 1024 * sizeof(u64);    // 16 KB
  const size_t flag_b     = (size_t)2 * 32 * sizeof(Flag);     // 4 KB

  const int fresh = (ws_size >= hrec_fresh + lrec_b + flag_b) ? 1 : 0;
  const size_t hsz = fresh ? hrec_fresh : hrec_par;

  u64*  hrec  = (u64*)d_ws;
  u64*  lrec  = (u64*)((char*)d_ws + hsz);
  Flag* flagH = (Flag*)((char*)d_ws + hsz + lrec_b);

  (void)hipFuncSetAttribute(
      reinterpret_cast<const void*>(&decoder_r13),
      hipFuncAttributeMaxDynamicSharedMemorySize, lds_bytes);
  decoder_r13<<<NB, TPB, lds_bytes, stream>>>(
      X, ENC, W_ih, W_hh, b_ih, b_hh, W_out, b_out, out,
      hrec, lrec, flagH, fresh);
}